// Round 1
// baseline (422.089 us; speedup 1.0000x reference)
//
#include <hip/hip_runtime.h>

#define NA    4
#define NT    64
#define NGH   76
#define NGW   136
#define NB    16
#define NCELLS (NA * NGH * NGW)   // 41344 anchor cells per batch

// One thread per anchor cell. blockIdx.y = batch.
__global__ __launch_bounds__(256) void yolo_assign_kernel(
    const float* __restrict__ targets,   // (NB, NT, 6): cls, tid, x, y, w, h
    const float* __restrict__ anchors,   // (NA, 2)
    const int*   __restrict__ img_w_p,   // scalar
    float* __restrict__ out)             // [tconf 16*41344][tbox *4][tid *1]
{
    __shared__ float s_gt[NT][4];    // gx, gy, gw, gh (grid units)
    __shared__ float s_tid[NT];
    __shared__ float s_anch[NA * 2]; // anchor_vec = anchors / stride

    const int b = blockIdx.y;
    const int t = threadIdx.x;

    if (t < NT) {
        const float* tp = targets + ((size_t)b * NT + t) * 6;
        float tid_v = tp[1];
        float gx = tp[2] * (float)NGW;
        float gy = tp[3] * (float)NGH;
        // jnp.clip(gxy, 0, scale-1)
        gx = fminf(fmaxf(gx, 0.0f), (float)NGW - 1.0f);
        gy = fminf(fmaxf(gy, 0.0f), (float)NGH - 1.0f);
        s_gt[t][0] = gx;
        s_gt[t][1] = gy;
        s_gt[t][2] = tp[4] * (float)NGW;
        s_gt[t][3] = tp[5] * (float)NGH;
        s_tid[t] = (float)(int)tid_v;   // t[:,1].astype(int32)
    }
    if (t < NA * 2) {
        float stride = (float)(*img_w_p) / (float)NGW;   // 1088/136 = 8
        s_anch[t] = anchors[t] / stride;
    }
    __syncthreads();

    const int cell = blockIdx.x * blockDim.x + t;
    if (cell >= NCELLS) return;

    const int a   = cell / (NGH * NGW);
    const int rem = cell % (NGH * NGW);
    const int gh  = rem / NGW;
    const int gw  = rem % NGW;

    const float px = (float)gw;
    const float py = (float)gh;
    const float pw = s_anch[a * 2 + 0];
    const float ph = s_anch[a * 2 + 1];

    const float p_xmin = px - pw * 0.5f;
    const float p_xmax = px + pw * 0.5f;
    const float p_ymin = py - ph * 0.5f;
    const float p_ymax = py + ph * 0.5f;
    const float a1 = pw * ph;

    float best = -1.0f;
    int   bidx = 0;
    #pragma unroll 8
    for (int j = 0; j < NT; ++j) {
        const float gx  = s_gt[j][0];
        const float gy  = s_gt[j][1];
        const float gww = s_gt[j][2];
        const float ghh = s_gt[j][3];
        float ix = fminf(p_xmax, gx + gww * 0.5f) - fmaxf(p_xmin, gx - gww * 0.5f);
        float iy = fminf(p_ymax, gy + ghh * 0.5f) - fmaxf(p_ymin, gy - ghh * 0.5f);
        ix = fmaxf(ix, 0.0f);
        iy = fmaxf(iy, 0.0f);
        const float inter = ix * iy;
        const float iou = inter / (a1 + gww * ghh - inter + 1e-16f);
        if (iou > best) { best = iou; bidx = j; }   // first-max like jnp.argmax
    }

    const bool fg  = best > 0.5f;
    const bool ign = (best < 0.5f) && (best > 0.4f);
    const float tconf = fg ? 1.0f : (ign ? -1.0f : 0.0f);

    float4 tbox = make_float4(0.0f, 0.0f, 0.0f, 0.0f);
    float  tid_out = -1.0f;   // fg & any(fg) == fg identically, no reduction needed
    if (fg) {
        const float gx  = s_gt[bidx][0];
        const float gy  = s_gt[bidx][1];
        const float gww = s_gt[bidx][2];
        const float ghh = s_gt[bidx][3];
        tbox.x = (gx - px) / pw;
        tbox.y = (gy - py) / ph;
        tbox.z = logf(gww / pw);
        tbox.w = logf(ghh / ph);
        tid_out = s_tid[bidx];
    }

    const size_t cidx = (size_t)b * NCELLS + cell;
    const size_t n_total = (size_t)NB * NCELLS;     // 661504

    out[cidx] = tconf;                               // tconf block
    float4* tbox_out = (float4*)(out + n_total);     // tbox block (16B aligned)
    tbox_out[cidx] = tbox;
    out[n_total * 5 + cidx] = tid_out;               // tid block
}

extern "C" void kernel_launch(void* const* d_in, const int* in_sizes, int n_in,
                              void* d_out, int out_size, void* d_ws, size_t ws_size,
                              hipStream_t stream) {
    // inputs: 0=p_cat (unused, shape-only), 1=targets, 2=anchors, 3=img_w, 4=img_h
    const float* targets = (const float*)d_in[1];
    const float* anchors = (const float*)d_in[2];
    const int*   img_w   = (const int*)d_in[3];
    float* out = (float*)d_out;

    dim3 block(256);
    dim3 grid((NCELLS + 255) / 256, NB);   // (162, 16)
    yolo_assign_kernel<<<grid, block, 0, stream>>>(targets, anchors, img_w, out);
}